// Round 1
// baseline (201.444 us; speedup 1.0000x reference)
//
#include <hip/hip_runtime.h>
#include <hip/hip_bf16.h>

#define LOG2PI 1.83787706640934548356f

typedef __attribute__((ext_vector_type(4))) float f32x4;
typedef __attribute__((ext_vector_type(8))) short bf16x8;
typedef __attribute__((ext_vector_type(8))) unsigned short u16x8;

__device__ __forceinline__ unsigned short f2bf(float f) {
    union { float f; unsigned u; } v; v.f = f;
    unsigned r = v.u + 0x7fffu + ((v.u >> 16) & 1u);   // RNE
    return (unsigned short)(r >> 16);
}
__device__ __forceinline__ float bf2f(unsigned short h) {
    union { unsigned u; float f; } v; v.u = ((unsigned)h) << 16; return v.f;
}

// LDS map: G bf16 [256][256] at byte 0 (row d, col e), swz ^((d&7)<<4)  -> 131072 B
//          diff bf16 [64][256] at byte 131072 (row r, col e), swz ^((r&7)<<4) -> 32768 B
#define DIFF_BASE 131072

__global__ __launch_bounds__(256, 1)
void k_maha(const float* __restrict__ x, const float* __restrict__ G,
            const float* __restrict__ means, float* __restrict__ maha)
{
    extern __shared__ char smem[];
    const int b    = blockIdx.x;
    const int tid  = threadIdx.x;
    const int lane = tid & 63;
    const int w    = tid >> 6;          // wave 0..3, owns cols [64w, 64w+64)
    const float* Gb = G + (size_t)b * 65536;
    const float* xb = x + b * 256;

    // ---- stage full G_b -> LDS bf16, swizzled ----
    {
        const int rsub = tid >> 5;            // 0..7
        const int e0   = (tid & 31) * 8;      // 0..248
        #pragma unroll 4
        for (int it = 0; it < 32; ++it) {
            const int d = it * 8 + rsub;
            const float* src = Gb + d * 256 + e0;
            f32x4 v0 = *reinterpret_cast<const f32x4*>(src);
            f32x4 v1 = *reinterpret_cast<const f32x4*>(src + 4);
            u16x8 h;
            h[0]=f2bf(v0[0]); h[1]=f2bf(v0[1]); h[2]=f2bf(v0[2]); h[3]=f2bf(v0[3]);
            h[4]=f2bf(v1[0]); h[5]=f2bf(v1[1]); h[6]=f2bf(v1[2]); h[7]=f2bf(v1[3]);
            const int byte = (d * 512 + e0 * 2) ^ ((d & 7) << 4);
            *reinterpret_cast<u16x8*>(smem + byte) = h;
        }
    }

    const int lrow = lane & 15;
    const int lk   = (lane >> 4) * 8;
    const int g    = lane >> 4;

    for (int chunk = 0; chunk < 16; ++chunk) {
        const int c0 = chunk * 64;
        __syncthreads();   // diff readers (prev epilogue) done; also covers G staging on chunk 0

        // ---- fill diff chunk [64][256] ----
        {
            const int r = tid >> 2;
            int cc = c0 + r; if (cc > 999) cc = 999;   // tail: clamp loads, skip stores later
            const float* mrow = means + cc * 256;
            const int ebase = (tid & 3) * 64;
            #pragma unroll
            for (int i = 0; i < 8; ++i) {
                const int e = ebase + i * 8;
                f32x4 m0 = *reinterpret_cast<const f32x4*>(mrow + e);
                f32x4 m1 = *reinterpret_cast<const f32x4*>(mrow + e + 4);
                f32x4 x0 = *reinterpret_cast<const f32x4*>(xb + e);
                f32x4 x1 = *reinterpret_cast<const f32x4*>(xb + e + 4);
                u16x8 h;
                h[0]=f2bf(x0[0]-m0[0]); h[1]=f2bf(x0[1]-m0[1]);
                h[2]=f2bf(x0[2]-m0[2]); h[3]=f2bf(x0[3]-m0[3]);
                h[4]=f2bf(x1[0]-m1[0]); h[5]=f2bf(x1[1]-m1[1]);
                h[6]=f2bf(x1[2]-m1[2]); h[7]=f2bf(x1[3]-m1[3]);
                const int byte = DIFF_BASE + ((r * 512 + e * 2) ^ ((r & 7) << 4));
                *reinterpret_cast<u16x8*>(smem + byte) = h;
            }
        }
        __syncthreads();

        // ---- GEMM: T'[c,d] = sum_e diff[c,e] * G[d,e] ----
        f32x4 acc[4][4];
        #pragma unroll
        for (int m = 0; m < 4; ++m)
            #pragma unroll
            for (int n = 0; n < 4; ++n)
                acc[m][n] = f32x4{0.f, 0.f, 0.f, 0.f};

        #pragma unroll
        for (int ks = 0; ks < 8; ++ks) {
            const int k = ks * 32 + lk;
            bf16x8 afr[4], bfr[4];
            #pragma unroll
            for (int m = 0; m < 4; ++m) {
                const int r = m * 16 + lrow;
                afr[m] = *reinterpret_cast<const bf16x8*>(
                    smem + DIFF_BASE + ((r * 512 + k * 2) ^ ((r & 7) << 4)));
            }
            #pragma unroll
            for (int n = 0; n < 4; ++n) {
                const int d = w * 64 + n * 16 + lrow;
                bfr[n] = *reinterpret_cast<const bf16x8*>(
                    smem + ((d * 512 + k * 2) ^ ((d & 7) << 4)));
            }
            #pragma unroll
            for (int m = 0; m < 4; ++m)
                #pragma unroll
                for (int n = 0; n < 4; ++n)
                    acc[m][n] = __builtin_amdgcn_mfma_f32_16x16x32_bf16(
                        afr[m], bfr[n], acc[m][n], 0, 0, 0);
        }

        // ---- epilogue: maha partial = sum_d T'[c,d]*diff[c,d] over this wave's 64 cols ----
        #pragma unroll
        for (int m = 0; m < 4; ++m) {
            float p0 = 0.f, p1 = 0.f, p2 = 0.f, p3 = 0.f;
            const int rb = m * 16 + g * 4;
            #pragma unroll
            for (int n = 0; n < 4; ++n) {
                const int dcol = w * 64 + n * 16 + lrow;
                float d0 = bf2f(*reinterpret_cast<const unsigned short*>(
                    smem + DIFF_BASE + (((rb+0) * 512 + dcol * 2) ^ (((rb+0) & 7) << 4))));
                float d1 = bf2f(*reinterpret_cast<const unsigned short*>(
                    smem + DIFF_BASE + (((rb+1) * 512 + dcol * 2) ^ (((rb+1) & 7) << 4))));
                float d2 = bf2f(*reinterpret_cast<const unsigned short*>(
                    smem + DIFF_BASE + (((rb+2) * 512 + dcol * 2) ^ (((rb+2) & 7) << 4))));
                float d3 = bf2f(*reinterpret_cast<const unsigned short*>(
                    smem + DIFF_BASE + (((rb+3) * 512 + dcol * 2) ^ (((rb+3) & 7) << 4))));
                p0 += acc[m][n][0] * d0;
                p1 += acc[m][n][1] * d1;
                p2 += acc[m][n][2] * d2;
                p3 += acc[m][n][3] * d3;
            }
            #pragma unroll
            for (int mask = 1; mask <= 8; mask <<= 1) {
                p0 += __shfl_xor(p0, mask);
                p1 += __shfl_xor(p1, mask);
                p2 += __shfl_xor(p2, mask);
                p3 += __shfl_xor(p3, mask);
            }
            if ((lane & 15) == 0) {
                const int cb = c0 + rb;
                if (cb + 0 < 1000) atomicAdd(&maha[b * 1000 + cb + 0], p0);
                if (cb + 1 < 1000) atomicAdd(&maha[b * 1000 + cb + 1], p1);
                if (cb + 2 < 1000) atomicAdd(&maha[b * 1000 + cb + 2], p2);
                if (cb + 3 < 1000) atomicAdd(&maha[b * 1000 + cb + 3], p3);
            }
        }
    }
}

__global__ __launch_bounds__(64)
void k_sumclv(const float* __restrict__ clv, float* __restrict__ sumclv)
{
    const int c = blockIdx.x;
    const int lane = threadIdx.x;
    const float* row = clv + c * 256;
    float s = row[lane] + row[lane + 64] + row[lane + 128] + row[lane + 192];
    #pragma unroll
    for (int mask = 1; mask < 64; mask <<= 1) s += __shfl_xor(s, mask);
    if (lane == 0) sumclv[c] = s;
}

// in-place: maha lives in d_out; each element read+written only by its own thread
__global__ __launch_bounds__(256)
void k_softmax(const float* __restrict__ maha, const float* __restrict__ lp,
               const float* __restrict__ sumclv, float* __restrict__ out)
{
    __shared__ float red[4];
    const int b = blockIdx.x, tid = threadIdx.x;
    const int lane = tid & 63, w = tid >> 6;
    float s[4];
    float mx = -3.4e38f;
    #pragma unroll
    for (int i = 0; i < 4; ++i) {
        const int c = tid + i * 256;
        if (c < 1000) {
            float v = -0.5f * (maha[b * 1000 + c] + sumclv[c] + 256.0f * LOG2PI) + lp[c];
            s[i] = v; mx = fmaxf(mx, v);
        } else s[i] = -3.4e38f;
    }
    #pragma unroll
    for (int mask = 1; mask < 64; mask <<= 1) mx = fmaxf(mx, __shfl_xor(mx, mask));
    if (lane == 0) red[w] = mx;
    __syncthreads();
    const float bm = fmaxf(fmaxf(red[0], red[1]), fmaxf(red[2], red[3]));
    __syncthreads();
    float se = 0.f;
    #pragma unroll
    for (int i = 0; i < 4; ++i) {
        const int c = tid + i * 256;
        if (c < 1000) se += expf(s[i] - bm);
    }
    #pragma unroll
    for (int mask = 1; mask < 64; mask <<= 1) se += __shfl_xor(se, mask);
    if (lane == 0) red[w] = se;
    __syncthreads();
    const float lse = bm + logf(red[0] + red[1] + red[2] + red[3]);
    #pragma unroll
    for (int i = 0; i < 4; ++i) {
        const int c = tid + i * 256;
        if (c < 1000) out[b * 1000 + c] = s[i] - lse;
    }
}

extern "C" void kernel_launch(void* const* d_in, const int* in_sizes, int n_in,
                              void* d_out, int out_size, void* d_ws, size_t ws_size,
                              hipStream_t stream)
{
    const float* x     = (const float*)d_in[0];
    const float* G     = (const float*)d_in[1];
    const float* lp    = (const float*)d_in[2];
    const float* means = (const float*)d_in[3];
    const float* clv   = (const float*)d_in[4];
    float* out    = (float*)d_out;
    float* sumclv = (float*)d_ws;              // 1000 f32

    hipFuncSetAttribute(reinterpret_cast<const void*>(k_maha),
                        hipFuncAttributeMaxDynamicSharedMemorySize, 163840);

    hipMemsetAsync(d_out, 0, (size_t)out_size * sizeof(float), stream);
    k_sumclv<<<1000, 64, 0, stream>>>(clv, sumclv);
    k_maha<<<256, 256, 163840, stream>>>(x, G, means, out);
    k_softmax<<<256, 256, 0, stream>>>(out, lp, sumclv, out);
}

// Round 6
// 171.264 us; speedup vs baseline: 1.1762x; 1.1762x over previous
//
#include <hip/hip_runtime.h>

#define LOG2PI 1.83787706640934548356f

typedef __attribute__((ext_vector_type(4))) float f32x4;
typedef __attribute__((ext_vector_type(2))) float f32x2;
typedef __attribute__((ext_vector_type(8))) short bf16x8;

__device__ __forceinline__ unsigned short f2bf(float f) {
    union { float f; unsigned u; } v; v.f = f;
    unsigned r = v.u + 0x7fffu + ((v.u >> 16) & 1u);   // RNE
    return (unsigned short)(r >> 16);
}
__device__ __forceinline__ float bf2f(unsigned short h) {
    union { unsigned u; float f; } v; v.u = ((unsigned)h) << 16; return v.f;
}
__device__ __forceinline__ bf16x8 pack8(f32x4 a, f32x4 b) {
    bf16x8 h;
    h[0]=(short)f2bf(a[0]); h[1]=(short)f2bf(a[1]); h[2]=(short)f2bf(a[2]); h[3]=(short)f2bf(a[3]);
    h[4]=(short)f2bf(b[0]); h[5]=(short)f2bf(b[1]); h[6]=(short)f2bf(b[2]); h[7]=(short)f2bf(b[3]);
    return h;
}
// sum within each 16-lane DPP row; valid in lane 15 of each row (VALU pipe, no LDS)
__device__ __forceinline__ float rowsum16(float v) {
    v += __int_as_float(__builtin_amdgcn_update_dpp(0, __float_as_int(v), 0x111, 0xf, 0xf, true));
    v += __int_as_float(__builtin_amdgcn_update_dpp(0, __float_as_int(v), 0x112, 0xf, 0xf, true));
    v += __int_as_float(__builtin_amdgcn_update_dpp(0, __float_as_int(v), 0x114, 0xf, 0xf, true));
    v += __int_as_float(__builtin_amdgcn_update_dpp(0, __float_as_int(v), 0x118, 0xf, 0xf, true));
    return v;
}

// bias[c] = lp[c] - 0.5*(sum(clv[c,:]) + 256*log(2pi))
__global__ __launch_bounds__(256)
void k_prep(const float* __restrict__ clv, const float* __restrict__ lp,
            float* __restrict__ bias)
{
    const int w = threadIdx.x >> 6, lane = threadIdx.x & 63;
    const int c = blockIdx.x * 4 + w;
    if (c >= 1000) return;
    f32x4 v = *reinterpret_cast<const f32x4*>(clv + c * 256 + lane * 4);
    float s = v[0] + v[1] + v[2] + v[3];
    #pragma unroll
    for (int m = 1; m < 64; m <<= 1) s += __shfl_xor(s, m);
    if (lane == 0) bias[c] = lp[c] - 0.5f * (s + 256.0f * LOG2PI);
}

// One block per batch. 8 waves: wm = wave>>2 (16-class row half), wn = wave&3 (64-col group).
// G_b held in registers as MFMA B-fragments (128 VGPR). LDS: double-buffered 32-class diff
// chunk in SoA-slice layout [slice 0..31][row 0..31][16B] (conflict-free b128 r/w) + maha.
__global__ __launch_bounds__(512, 2)
void k_main(const float* __restrict__ x, const float* __restrict__ G,
            const float* __restrict__ means, const float* __restrict__ bias,
            float* __restrict__ out)
{
    __shared__ char dbuf[2][16384];
    __shared__ float maha[1024];
    __shared__ float red[8];

    const int b    = blockIdx.x;
    const int tid  = threadIdx.x;
    const int lane = tid & 63;
    const int wave = tid >> 6;
    const int wm   = wave >> 2;
    const int wn   = wave & 3;
    const int lrow = lane & 15;
    const int g    = lane >> 4;

    const float* Gb = G + (size_t)b * 65536;
    const float* xb = x + b * 256;

    maha[tid] = 0.f; maha[tid + 512] = 0.f;

    // ---- G -> register B-fragments: greg[n][ks], lane holds G[d=64wn+16n+lrow][32ks+8g .. +8)
    bf16x8 greg[4][8];
    #pragma unroll
    for (int n = 0; n < 4; ++n) {
        const float* rowp = Gb + (size_t)(wn * 64 + n * 16 + lrow) * 256 + g * 8;
        #pragma unroll
        for (int ks = 0; ks < 8; ++ks) {
            f32x4 v0 = *reinterpret_cast<const f32x4*>(rowp + ks * 32);
            f32x4 v1 = *reinterpret_cast<const f32x4*>(rowp + ks * 32 + 4);
            greg[n][ks] = pack8(v0, v1);
        }
    }

    // staging map: row sr = tid&31, slices ss and ss+16 (ss = tid>>5 in 0..15)
    const int sr = tid & 31;
    const int ss = tid >> 5;
    const f32x4 x0a = *reinterpret_cast<const f32x4*>(xb + ss * 8);
    const f32x4 x0b = *reinterpret_cast<const f32x4*>(xb + ss * 8 + 4);
    const f32x4 x1a = *reinterpret_cast<const f32x4*>(xb + (ss + 16) * 8);
    const f32x4 x1b = *reinterpret_cast<const f32x4*>(xb + (ss + 16) * 8 + 4);

    f32x4 r0a, r0b, r1a, r1b;
    auto load_chunk = [&](int c0) {
        int cc = c0 + sr; if (cc > 999) cc = 999;
        const float* mp = means + (size_t)cc * 256;
        r0a = *reinterpret_cast<const f32x4*>(mp + ss * 8);
        r0b = *reinterpret_cast<const f32x4*>(mp + ss * 8 + 4);
        r1a = *reinterpret_cast<const f32x4*>(mp + (ss + 16) * 8);
        r1b = *reinterpret_cast<const f32x4*>(mp + (ss + 16) * 8 + 4);
    };
    auto write_chunk = [&](int bufi) {
        *reinterpret_cast<bf16x8*>(dbuf[bufi] + (ss * 32 + sr) * 16)        = pack8(x0a - r0a, x0b - r0b);
        *reinterpret_cast<bf16x8*>(dbuf[bufi] + ((ss + 16) * 32 + sr) * 16) = pack8(x1a - r1a, x1b - r1b);
    };

    load_chunk(0);

    for (int t = 0; t < 32; ++t) {
        write_chunk(t & 1);
        __syncthreads();                    // single barrier per chunk (see liveness argument)
        if (t < 31) load_chunk((t + 1) * 32);   // T14: issue early, consume next top

        const char* buf = dbuf[t & 1];
        f32x4 acc[4];
        #pragma unroll
        for (int n = 0; n < 4; ++n) acc[n] = f32x4{0.f, 0.f, 0.f, 0.f};

        #pragma unroll
        for (int ks = 0; ks < 8; ++ks) {
            // A-frag: diff[row=16wm+lrow][e=32ks+8g ..) — 16-lane contiguous read
            bf16x8 afr = *reinterpret_cast<const bf16x8*>(
                buf + ((ks * 4 + g) * 32 + wm * 16 + lrow) * 16);
            #pragma unroll
            for (int n = 0; n < 4; ++n)
                acc[n] = __builtin_amdgcn_mfma_f32_16x16x32_bf16(afr, greg[n][ks], acc[n], 0, 0, 0);
        }

        // epilogue: p_i = sum over this wave's 64 cols of T[c,d]*diff[c,d]
        float p[4] = {0.f, 0.f, 0.f, 0.f};
        #pragma unroll
        for (int n = 0; n < 4; ++n) {
            const int col = wn * 64 + n * 16 + lrow;
            const char* dp = buf + ((col >> 3) * 32) * 16 + (col & 7) * 2;
            #pragma unroll
            for (int i = 0; i < 4; ++i) {
                const int row = wm * 16 + g * 4 + i;
                p[i] += acc[n][i] * bf2f(*reinterpret_cast<const unsigned short*>(dp + row * 16));
            }
        }
        #pragma unroll
        for (int i = 0; i < 4; ++i) p[i] = rowsum16(p[i]);
        if (lrow == 15) {
            const int c = t * 32 + wm * 16 + g * 4;
            #pragma unroll
            for (int i = 0; i < 4; ++i)
                if (c + i < 1000) atomicAdd(&maha[c + i], p[i]);
        }
    }

    __syncthreads();

    // ---- fused log-softmax over maha[0..999] ----
    const int c2 = tid * 2;
    float a0 = -3.0e38f, a1 = -3.0e38f;
    if (c2 < 1000) {
        f32x2 mh = *reinterpret_cast<const f32x2*>(&maha[c2]);
        f32x2 bi = *reinterpret_cast<const f32x2*>(bias + c2);
        a0 = -0.5f * mh[0] + bi[0];
        a1 = -0.5f * mh[1] + bi[1];
    }
    float mx = fmaxf(a0, a1);
    #pragma unroll
    for (int m = 1; m < 64; m <<= 1) mx = fmaxf(mx, __shfl_xor(mx, m));
    if (lane == 0) red[wave] = mx;
    __syncthreads();
    float bm = red[0];
    #pragma unroll
    for (int i = 1; i < 8; ++i) bm = fmaxf(bm, red[i]);
    __syncthreads();
    float se = 0.f;
    if (c2 < 1000) se = expf(a0 - bm) + expf(a1 - bm);
    #pragma unroll
    for (int m = 1; m < 64; m <<= 1) se += __shfl_xor(se, m);
    if (lane == 0) red[wave] = se;
    __syncthreads();
    float ssum = red[0];
    #pragma unroll
    for (int i = 1; i < 8; ++i) ssum += red[i];
    const float lse = bm + logf(ssum);
    if (c2 < 1000) {
        f32x2 o; o[0] = a0 - lse; o[1] = a1 - lse;
        *reinterpret_cast<f32x2*>(out + (size_t)b * 1000 + c2) = o;
    }
}

extern "C" void kernel_launch(void* const* d_in, const int* in_sizes, int n_in,
                              void* d_out, int out_size, void* d_ws, size_t ws_size,
                              hipStream_t stream)
{
    const float* x     = (const float*)d_in[0];
    const float* G     = (const float*)d_in[1];
    const float* lp    = (const float*)d_in[2];
    const float* means = (const float*)d_in[3];
    const float* clv   = (const float*)d_in[4];
    float* out  = (float*)d_out;
    float* bias = (float*)d_ws;   // 1000 f32

    k_prep<<<250, 256, 0, stream>>>(clv, lp, bias);
    k_main<<<256, 512, 0, stream>>>(x, G, means, bias, out);
}